// Round 6
// baseline (587.272 us; speedup 1.0000x reference)
//
#include <hip/hip_runtime.h>
#include <hip/hip_bf16.h>
#include <math.h>

typedef __attribute__((ext_vector_type(8))) short short8;
typedef __attribute__((ext_vector_type(4))) float f32x4;

constexpr int nB = 64, nT = 512, nE = 768, nH = 128, nG = 512, nC = 18;
constexpr int nBT = nB * nT;
constexpr int N_LSTM_BLK = 32, N_PROJ_BLK = 1024;

__device__ __forceinline__ float bf2f(unsigned short u) { return __uint_as_float(((unsigned int)u) << 16); }
__device__ __forceinline__ unsigned short f2bf(float f) {
  __hip_bfloat16 h = __float2bfloat16(f);
  return *reinterpret_cast<unsigned short*>(&h);
}
__device__ __forceinline__ float rlane(float v, int lane) {
  return __uint_as_float(__builtin_amdgcn_readlane(__float_as_uint(v), lane));
}
__device__ __forceinline__ float fast_sig(float x) {
  return __builtin_amdgcn_rcpf(1.0f + __builtin_amdgcn_exp2f(-1.44269504f * x));
}
__device__ __forceinline__ float fast_tanh(float x) {
  return 1.0f - 2.0f * __builtin_amdgcn_rcpf(1.0f + __builtin_amdgcn_exp2f(2.88539008f * x));
}
__device__ __forceinline__ float fast_exp(float x) { return __builtin_amdgcn_exp2f(1.44269504f * x); }
__device__ __forceinline__ float fast_log(float x) { return __builtin_amdgcn_logf(x) * 0.69314718f; }

// ---------------- f32 -> bf16 convert (weights only) ----------------
__global__ __launch_bounds__(256) void cvt_kernel(const float* __restrict__ in,
                                                  unsigned short* __restrict__ out, int n8) {
  int i = blockIdx.x * blockDim.x + threadIdx.x;
  const int stride = gridDim.x * blockDim.x;
  for (; i < n8; i += stride) {
    const float4 a = ((const float4*)in)[(size_t)i * 2];
    const float4 b = ((const float4*)in)[(size_t)i * 2 + 1];
    unsigned short u[8] = {f2bf(a.x), f2bf(a.y), f2bf(a.z), f2bf(a.w),
                           f2bf(b.x), f2bf(b.y), f2bf(b.z), f2bf(b.w)};
    ((float4*)out)[i] = *(float4*)u;
  }
}

// ================= fused proj + lstm (producer/consumer via flags) =================
// blocks [0, 32): lstm consumers (4 batches x 1 dir each), spin on per-quarter flags.
// blocks [32, 1056): proj producers, 128x256 tiles, priority rounds:
//   round p produces fwd quarter p and bwd quarter 3-p.
// flags[(dir*64 + b)*4 + tq] counts completed col-halves (target 2).
__global__ __launch_bounds__(512, 2) void fused_kernel(
    const float* __restrict__ x,
    const unsigned short* __restrict__ wfb, const unsigned short* __restrict__ wbb,
    const float* __restrict__ biasF, const float* __restrict__ biasB,
    unsigned short* __restrict__ Pf, unsigned short* __restrict__ Pb,
    const float* __restrict__ WhhF, const float* __restrict__ WhhB,
    unsigned short* __restrict__ hf, unsigned short* __restrict__ hb,
    int* __restrict__ flags)
{
  __shared__ __align__(16) unsigned short smem[15360];  // 30 KB
  const int tid = threadIdx.x;

  if (blockIdx.x >= N_LSTM_BLK) {
    // ---------------- producer: proj tile 128 rows x 256 cols ----------------
    const int p = blockIdx.x - N_LSTM_BLK;
    const int round = p >> 8;           // 0..3
    const int r = p & 255;
    const int dir = r & 1;
    const int rem = r >> 1;             // 0..127
    const int b = rem >> 1;             // batch 0..63
    const int snt = rem & 1;            // col half
    const int tq = dir ? (3 - round) : round;
    const unsigned short* W = dir ? wbb : wfb;
    const float* bias = dir ? biasB : biasF;
    unsigned short* P = dir ? Pb : Pf;
    const int m0 = b * nT + tq * 128;   // row offset into [nBT]
    const int n0 = snt * 256;

    unsigned short* As = smem;          // 128 x 40
    unsigned short* Bs = smem + 5120;   // 256 x 40

    const int w = tid >> 6, lane = tid & 63, l15 = lane & 15, l4 = lane >> 4;
    const int wr = w >> 2, wc = w & 3;
    const int arow = tid >> 2, aq = tid & 3;       // A: 128 rows x 4 quarters of 8
    const int brow = tid >> 1, bh = tid & 1;       // B: 256 rows x 2 halves of 16

    const float* srcA = x + (size_t)(m0 + arow) * nE + aq * 8;
    const unsigned short* srcB = W + (size_t)(n0 + brow) * nE + bh * 16;

    f32x4 acc[4][4];
#pragma unroll
    for (int i = 0; i < 4; ++i)
#pragma unroll
      for (int j = 0; j < 4; ++j) acc[i][j] = (f32x4){0.f, 0.f, 0.f, 0.f};

    for (int k0 = 0; k0 < nE; k0 += 32) {
      const float4 a0 = *(const float4*)(srcA + k0);
      const float4 a1 = *(const float4*)(srcA + k0 + 4);
      const float4 b0 = *(const float4*)(srcB + k0);
      const float4 b1 = *(const float4*)(srcB + k0 + 8);
      unsigned short ua[8] = {f2bf(a0.x), f2bf(a0.y), f2bf(a0.z), f2bf(a0.w),
                              f2bf(a1.x), f2bf(a1.y), f2bf(a1.z), f2bf(a1.w)};
      __syncthreads();
      *(float4*)&As[arow * 40 + aq * 8] = *(float4*)ua;
      *(float4*)&Bs[brow * 40 + bh * 16] = b0;
      *(float4*)&Bs[brow * 40 + bh * 16 + 8] = b1;
      __syncthreads();
      short8 af[4], bfr[4];
#pragma unroll
      for (int i = 0; i < 4; ++i) af[i] = *(const short8*)&As[(wr * 64 + i * 16 + l15) * 40 + l4 * 8];
#pragma unroll
      for (int j = 0; j < 4; ++j) bfr[j] = *(const short8*)&Bs[(wc * 64 + j * 16 + l15) * 40 + l4 * 8];
#pragma unroll
      for (int i = 0; i < 4; ++i)
#pragma unroll
        for (int j = 0; j < 4; ++j)
          acc[i][j] = __builtin_amdgcn_mfma_f32_16x16x32_bf16(af[i], bfr[j], acc[i][j], 0, 0, 0);
    }
    float bv[4];
#pragma unroll
    for (int j = 0; j < 4; ++j) bv[j] = bias[n0 + wc * 64 + j * 16 + l15];
#pragma unroll
    for (int i = 0; i < 4; ++i) {
#pragma unroll
      for (int j = 0; j < 4; ++j) {
        const int col = n0 + wc * 64 + j * 16 + l15;
#pragma unroll
        for (int rr = 0; rr < 4; ++rr) {
          const int row = m0 + wr * 64 + i * 16 + l4 * 4 + rr;
          P[(size_t)row * nG + col] = f2bf(acc[i][j][rr] + bv[j]);
        }
      }
    }
    __syncthreads();  // all waves' stores drained (vmcnt) before release
    if (tid == 0)
      __hip_atomic_fetch_add(&flags[(dir * 64 + b) * 4 + tq], 1,
                             __ATOMIC_RELEASE, __HIP_MEMORY_SCOPE_AGENT);
    return;
  }

  // ---------------- consumer: MFMA LSTM v4 + quarter waits ----------------
  const int bid = blockIdx.x;
  const int dir = bid & 1, grp = bid >> 1;
  const int b0 = grp * 4;
  const unsigned short* pre = dir ? Pb : Pf;
  const float* Whh = dir ? WhhB : WhhF;
  unsigned short* hout = dir ? hb : hf;

  const int w = tid >> 6, lane = tid & 63;
  const int l15 = lane & 15, l4 = lane >> 4;
  const int batch = l15 & 3, msel = l15 >> 2;
  const int cell = w * 16 + msel * 4 + l4;
  const int swz = batch * 40;

  unsigned short* h_lds = smem;  // 1024 shorts used

  short8 Af[4][4];
#pragma unroll
  for (int m = 0; m < 4; ++m) {
    const int gp = w * 64 + m * 16 + l15;
    const int gorig = (gp & 3) * 128 + (gp >> 2);
#pragma unroll
    for (int kk = 0; kk < 4; ++kk) {
      const float* wp = Whh + (size_t)gorig * nH + kk * 32 + l4 * 8;
      const float4 v0 = *(const float4*)wp;
      const float4 v1 = *(const float4*)(wp + 4);
      unsigned short u[8] = {f2bf(v0.x), f2bf(v0.y), f2bf(v0.z), f2bf(v0.w),
                             f2bf(v1.x), f2bf(v1.y), f2bf(v1.z), f2bf(v1.w)};
      Af[m][kk] = *(short8*)u;
    }
  }
  for (int i = tid; i < 2 * 4 * 128; i += 512) h_lds[i] = 0;
  __syncthreads();

#define WAIT_QUARTER(QL)                                                         \
  {                                                                              \
    const int tq_ = dir ? (3 - (QL)) : (QL);                                     \
    for (int bq_ = 0; bq_ < 4; ++bq_) {                                          \
      while (__hip_atomic_load(&flags[(dir * 64 + b0 + bq_) * 4 + tq_],          \
                               __ATOMIC_ACQUIRE, __HIP_MEMORY_SCOPE_AGENT) < 2)  \
        __builtin_amdgcn_s_sleep(8);                                             \
    }                                                                            \
  }

  WAIT_QUARTER(0)

  float c_state = 0.f;
  const unsigned short* pbase = pre + (size_t)(b0 + batch) * nT * nG + cell;

  unsigned short pA[4], pB[4];
  {
    const int tt0 = dir ? (nT - 1) : 0;
    const int tt1 = dir ? (nT - 2) : 1;
#pragma unroll
    for (int r = 0; r < 4; ++r) pA[r] = pbase[(size_t)tt0 * nG + r * 128];
#pragma unroll
    for (int r = 0; r < 4; ++r) pB[r] = pbase[(size_t)tt1 * nG + r * 128];
  }

#define LSTM_STEP(RB, T, BUFC)                                                   \
  {                                                                              \
    const int ttime = dir ? (nT - 1 - (T)) : (T);                                \
    float pg[4];                                                                 \
    _Pragma("unroll")                                                            \
    for (int r = 0; r < 4; ++r) pg[r] = bf2f(BUFC[r]);                           \
    {                                                                            \
      const int tl = ((T) + 2 < nT) ? (T) + 2 : (T);                             \
      const int ttl = dir ? (nT - 1 - tl) : tl;                                  \
      _Pragma("unroll")                                                          \
      for (int r = 0; r < 4; ++r) BUFC[r] = pbase[(size_t)ttl * nG + r * 128];   \
    }                                                                            \
    short8 bfr[4];                                                               \
    _Pragma("unroll")                                                            \
    for (int kk = 0; kk < 4; ++kk) {                                             \
      const int idx = (RB) * 512 + batch * 128 + ((kk * 32 + l4 * 8) ^ swz);     \
      bfr[kk] = *(const short8*)&h_lds[idx];                                     \
    }                                                                            \
    f32x4 acc[4];                                                                \
    _Pragma("unroll")                                                            \
    for (int m = 0; m < 4; ++m) acc[m] = (f32x4){0.f, 0.f, 0.f, 0.f};            \
    _Pragma("unroll")                                                            \
    for (int kk = 0; kk < 4; ++kk)                                               \
      _Pragma("unroll")                                                          \
      for (int m = 0; m < 4; ++m)                                                \
        acc[m] = __builtin_amdgcn_mfma_f32_16x16x32_bf16(Af[m][kk], bfr[kk], acc[m], 0, 0, 0); \
    const float g0 = msel < 2 ? (msel == 0 ? acc[0][0] : acc[1][0]) : (msel == 2 ? acc[2][0] : acc[3][0]); \
    const float g1 = msel < 2 ? (msel == 0 ? acc[0][1] : acc[1][1]) : (msel == 2 ? acc[2][1] : acc[3][1]); \
    const float g2 = msel < 2 ? (msel == 0 ? acc[0][2] : acc[1][2]) : (msel == 2 ? acc[2][2] : acc[3][2]); \
    const float g3 = msel < 2 ? (msel == 0 ? acc[0][3] : acc[1][3]) : (msel == 2 ? acc[2][3] : acc[3][3]); \
    const float gi = g0 + pg[0], gf = g1 + pg[1], gg = g2 + pg[2], go = g3 + pg[3]; \
    c_state = fast_sig(gf) * c_state + fast_sig(gi) * fast_tanh(gg);             \
    const float hval = fast_sig(go) * fast_tanh(c_state);                        \
    const unsigned short hu = f2bf(hval);                                        \
    h_lds[((RB) ^ 1) * 512 + batch * 128 + (cell ^ swz)] = hu;                   \
    hout[((size_t)(b0 + batch) * nT + ttime) * nH + cell] = hu;                  \
    asm volatile("s_waitcnt lgkmcnt(0)" ::: "memory");                           \
    __builtin_amdgcn_sched_barrier(0);                                           \
    __builtin_amdgcn_s_barrier();                                                \
  }

  for (int t2 = 0; t2 < nT; t2 += 2) {
    if ((t2 & 127) == 126 && t2 + 2 < nT) WAIT_QUARTER((t2 + 2) >> 7)
    LSTM_STEP(0, t2, pA)
    LSTM_STEP(1, t2 + 1, pB)
  }
#undef LSTM_STEP
#undef WAIT_QUARTER
}

// ---------------- emissions: em = [hf|hb] @ Wfc^T + bfc ----------------
__global__ __launch_bounds__(256) void em_kernel(
    const unsigned short* __restrict__ hf, const unsigned short* __restrict__ hb,
    const float* __restrict__ Wfc, const float* __restrict__ bfc,
    float* __restrict__ em)
{
  __shared__ float seq[32][260];
  __shared__ float Wf[18][260];
  const int tid = threadIdx.x;
  const int row0 = blockIdx.x * 32;
  for (int i = tid; i < 32 * 32; i += 256) {
    const int r = i >> 5, seg = i & 31;
    const unsigned short* src = (seg < 16) ? (hf + (size_t)(row0 + r) * nH + seg * 8)
                                           : (hb + (size_t)(row0 + r) * nH + (seg - 16) * 8);
    const float4 v = *(const float4*)src;
    const unsigned short* u = (const unsigned short*)&v;
#pragma unroll
    for (int k = 0; k < 8; ++k) seq[r][seg * 8 + k] = bf2f(u[k]);
  }
  for (int i = tid; i < nC * 256; i += 256) {
    const int cc = i >> 8, k = i & 255;
    Wf[cc][k] = Wfc[cc * 256 + k];
  }
  __syncthreads();
  for (int o = tid; o < 32 * nC; o += 256) {
    const int r = o / nC, cc = o - r * nC;
    float acc = bfc[cc];
    const float4* s4 = (const float4*)&seq[r][0];
    const float4* w4 = (const float4*)&Wf[cc][0];
#pragma unroll
    for (int q = 0; q < 64; ++q) {
      const float4 a = s4[q]; const float4 wv = w4[q];
      acc += a.x * wv.x + a.y * wv.y + a.z * wv.z + a.w * wv.w;
    }
    em[(size_t)(row0 + r) * nC + cc] = acc;
  }
}

// ---------------- fused CRF + Viterbi (register recurrences) ----------------
__global__ __launch_bounds__(128) void crfvit_kernel(
    const float* __restrict__ em, const int* __restrict__ labels,
    const int* __restrict__ mask, const float* __restrict__ start,
    const float* __restrict__ endt, const float* __restrict__ trans,
    float* __restrict__ llh, float* __restrict__ out_path)
{
  const int b = blockIdx.x; const int tid = threadIdx.x;
  __shared__ float tr[nC * nC];
  __shared__ unsigned char bp[(nT - 1) * nC];
  __shared__ unsigned char path[nT];
  for (int i = tid; i < nC * nC; i += 128) tr[i] = trans[i];
  __syncthreads();
  const float* eb = em + (size_t)b * nT * nC;

#define MAX18(c) fmaxf(fmaxf(fmaxf(fmaxf(fmaxf(c[0], c[1]), c[2]), fmaxf(fmaxf(c[3], c[4]), c[5])),           \
                             fmaxf(fmaxf(fmaxf(c[6], c[7]), c[8]), fmaxf(fmaxf(c[9], c[10]), c[11]))),        \
                       fmaxf(fmaxf(fmaxf(c[12], c[13]), c[14]), fmaxf(fmaxf(c[15], c[16]), c[17])))

  if (tid < 64) {
    const int l = tid;
    const int lc = l < nC ? l : nC - 1;
    const int* tg = labels + (size_t)b * nT;
    const int* mk = mask + (size_t)b * nT;

    float np = 0.f; int cnt = 0;
    for (int t = l; t < nT; t += 64) {
      const int tag = tg[t];
      const float e = eb[(size_t)t * nC + tag];
      if (t == 0) np += start[tag] + e;
      else np += (float)mk[t] * (e + tr[tg[t - 1] * nC + tag]);
      cnt += mk[t];
    }
#pragma unroll
    for (int off = 32; off; off >>= 1) { np += __shfl_xor(np, off); cnt += __shfl_xor(cnt, off); }
    const float num = np + endt[tg[cnt - 1]];

    float trc[nC];
#pragma unroll
    for (int i = 0; i < nC; ++i) trc[i] = tr[i * nC + lc];

    float alpha_r = start[lc] + eb[lc];
    float eA = eb[1 * nC + lc];
    float eB = eb[2 * nC + lc];
    float eC = eb[3 * nC + lc];
    for (int tk = 0; tk < 8; ++tk) {
      const unsigned long long mb = __ballot(mk[tk * 64 + l] != 0);
      for (int tt = (tk == 0 ? 1 : 0); tt < 64; ++tt) {
        const int t = tk * 64 + tt;
        const float ecur = eA; eA = eB; eB = eC;
        const int tl = t + 3 < nT ? t + 3 : nT - 1;
        eC = eb[(size_t)tl * nC + lc];
        float cand[nC];
#pragma unroll
        for (int i = 0; i < nC; ++i) cand[i] = rlane(alpha_r, i) + trc[i];
        const float m = MAX18(cand);
        float ex[nC];
#pragma unroll
        for (int i = 0; i < nC; ++i) ex[i] = fast_exp(cand[i] - m);
        float s = 0.f;
#pragma unroll
        for (int i = 0; i < nC; ++i) s += ex[i];
        const float anew = m + fast_log(s) + ecur;
        alpha_r = ((mb >> tt) & 1) ? anew : alpha_r;
      }
    }
    const float v = (l < nC) ? (alpha_r + endt[l]) : -3.0e38f;
    float m = v;
#pragma unroll
    for (int off = 32; off; off >>= 1) m = fmaxf(m, __shfl_xor(m, off));
    float s = (l < nC) ? fast_exp(v - m) : 0.f;
#pragma unroll
    for (int off = 32; off; off >>= 1) s += __shfl_xor(s, off);
    if (l == 0) llh[b] = num - (m + fast_log(s));
  } else {
    const int l = tid - 64;
    const int lc = l < nC ? l : nC - 1;
    float trc[nC];
#pragma unroll
    for (int i = 0; i < nC; ++i) trc[i] = tr[i * nC + lc];

    float score_r = start[lc] + eb[lc];
    float eA = eb[1 * nC + lc];
    float eB = eb[2 * nC + lc];
    float eC = eb[3 * nC + lc];
    for (int t = 1; t < nT; ++t) {
      const float ecur = eA; eA = eB; eB = eC;
      const int tl = t + 3 < nT ? t + 3 : nT - 1;
      eC = eb[(size_t)tl * nC + lc];
      float cand[nC];
#pragma unroll
      for (int i = 0; i < nC; ++i) cand[i] = rlane(score_r, i) + trc[i];
      const float m = MAX18(cand);
      int sel[nC];
#pragma unroll
      for (int i = 0; i < nC; ++i) sel[i] = (cand[i] == m) ? i : 63;
      int arg = sel[0];
#pragma unroll
      for (int i = 1; i < nC; ++i) arg = min(arg, sel[i]);
      score_r = m + ecur;
      if (l < nC) bp[(t - 1) * nC + l] = (unsigned char)arg;
    }
    if (l == 0) {
      float mm = -3.0e38f; int last = 0;
      for (int i = 0; i < nC; ++i) {
        const float v = rlane(score_r, i) + endt[i];
        if (v > mm) { mm = v; last = i; }
      }
      path[nT - 1] = (unsigned char)last;
      int cur = last;
      for (int t = nT - 2; t >= 0; --t) { cur = bp[t * nC + cur]; path[t] = (unsigned char)cur; }
    }
    asm volatile("s_waitcnt lgkmcnt(0)" ::: "memory");
    __builtin_amdgcn_wave_barrier();
    for (int t = l; t < nT; t += 64) out_path[(size_t)b * nT + t] = (float)(path[t] + 1);
  }
#undef MAX18
}

// ---------------- loss finalize ----------------
__global__ __launch_bounds__(64) void loss_kernel(const float* __restrict__ llh, float* __restrict__ out)
{
  const int l = threadIdx.x;
  float v = llh[l];
#pragma unroll
  for (int off = 32; off; off >>= 1) v += __shfl_xor(v, off);
  if (l == 0) out[0] = -v / (float)nB;
}

extern "C" void kernel_launch(void* const* d_in, const int* in_sizes, int n_in,
                              void* d_out, int out_size, void* d_ws, size_t ws_size,
                              hipStream_t stream)
{
  const float* x      = (const float*)d_in[0];
  const int*   amask  = (const int*)d_in[1];
  const int*   labels = (const int*)d_in[2];
  const float* Wih_f  = (const float*)d_in[3];
  const float* Whh_f  = (const float*)d_in[4];
  const float* b_f    = (const float*)d_in[5];
  const float* Wih_b  = (const float*)d_in[6];
  const float* Whh_b  = (const float*)d_in[7];
  const float* b_b    = (const float*)d_in[8];
  const float* Wfc    = (const float*)d_in[9];
  const float* bfc    = (const float*)d_in[10];
  const float* start  = (const float*)d_in[11];
  const float* endt   = (const float*)d_in[12];
  const float* trans  = (const float*)d_in[13];

  float* out = (float*)d_out;
  float* ws = (float*)d_ws;
  unsigned short* preF = (unsigned short*)ws;                       // 16.7M bf16
  unsigned short* preB = preF + (size_t)nBT * nG;                   // 16.7M bf16
  unsigned short* hf   = preB + (size_t)nBT * nG;                   // 4.2M bf16
  unsigned short* hb   = hf + (size_t)nBT * nH;                     // 4.2M bf16
  float* em  = (float*)(hb + (size_t)nBT * nH);                     // 590K f32
  float* llh = em + (size_t)nBT * nC;                               // 64 f32
  unsigned short* wfb = (unsigned short*)(llh + 64);                // 393K bf16
  unsigned short* wbb = wfb + (size_t)nG * nE;                      // 393K bf16
  int* flags = (int*)(wbb + (size_t)nG * nE);                       // 512 int

  hipMemsetAsync(flags, 0, 512 * sizeof(int), stream);
  cvt_kernel<<<192, 256, 0, stream>>>(Wih_f, wfb, nG * nE / 8);
  cvt_kernel<<<192, 256, 0, stream>>>(Wih_b, wbb, nG * nE / 8);
  fused_kernel<<<N_LSTM_BLK + N_PROJ_BLK, 512, 0, stream>>>(
      x, wfb, wbb, b_f, b_b, preF, preB, Whh_f, Whh_b, hf, hb, flags);
  em_kernel<<<1024, 256, 0, stream>>>(hf, hb, Wfc, bfc, em);
  crfvit_kernel<<<64, 128, 0, stream>>>(em, labels, amask, start, endt, trans, llh, out);
  loss_kernel<<<1, 64, 0, stream>>>(llh, out + nBT);
}